// Round 1
// baseline (195378.345 us; speedup 1.0000x reference)
//
#include <hip/hip_runtime.h>
#include <math.h>

#define Bz 16
#define Tz 1024
#define Ez 768
#define E3 2304
#define Vz 50257
#define NB 192
#define LN_EPS 1e-5f
#define EP 772   // padded LDS row stride (floats)

__device__ __forceinline__ float dot4acc(float acc, float4 w, float4 h){
  acc = fmaf(w.x,h.x,acc); acc = fmaf(w.y,h.y,acc);
  acc = fmaf(w.z,h.z,acc); acc = fmaf(w.w,h.w,acc);
  return acc;
}
__device__ __forceinline__ float sigm(float x){ return 1.0f/(1.0f+expf(-x)); }
// r=sig(ir+hr); z=sig(iz+hz); n=tanh(in + r*hn); h' = n + z*(hp-n)
__device__ __forceinline__ float gru_h(float ir,float iz,float in_,
                                       float hr,float hz,float hn,float hp){
  float r = sigm(ir+hr);
  float z = sigm(iz+hz);
  float n = tanhf(fmaf(r,hn,in_));
  return fmaf(z, hp-n, n);
}

__device__ __forceinline__ void grid_barrier(unsigned* cnt, unsigned target){
  __syncthreads();
  if (threadIdx.x==0){
    __hip_atomic_fetch_add(cnt, 1u, __ATOMIC_ACQ_REL, __HIP_MEMORY_SCOPE_AGENT);
    while (__hip_atomic_load(cnt, __ATOMIC_ACQUIRE, __HIP_MEMORY_SCOPE_AGENT) < target){
      __builtin_amdgcn_s_sleep(1);
    }
  }
  __syncthreads();
}

// Computes rows [r, r+NR) of out[b, :] = sVec[b,:] @ Wm[row,:]^T + bias, for all 16 b.
// lane layout: bb = lane&15 (batch), gq = lane>>4 (4 col-groups), cols c = gq*4 + 16*j.
template<int NR>
__device__ __forceinline__ void mm_rows(const float* __restrict__ Wm,
                                        const float* __restrict__ bias,
                                        const float (&sVec)[Bz][EP],
                                        float* __restrict__ outp,
                                        int r, int bb, int gq){
  float acc[NR];
#pragma unroll
  for (int k=0;k<NR;k++) acc[k]=0.f;
#pragma unroll 4
  for (int j=0;j<48;j++){
    const int c = (gq<<2) + (j<<4);
    const float4 hv = *(const float4*)(&sVec[bb][c]);
#pragma unroll
    for (int k=0;k<NR;k++){
      const float4 wv = *(const float4*)(Wm + (size_t)(r+k)*Ez + c);
      acc[k] = dot4acc(acc[k], wv, hv);
    }
  }
#pragma unroll
  for (int k=0;k<NR;k++){
    acc[k] += __shfl_xor(acc[k], 16);
    acc[k] += __shfl_xor(acc[k], 32);
  }
  if (gq==0){
#pragma unroll
    for (int k=0;k<NR;k++) outp[bb*E3 + r + k] = acc[k] + bias[r+k];
  }
}

// Persistent cooperative scan over T steps.
// Block groups (64 blocks each): 0 -> gi0 (x_t @ Wih0^T), 1 -> gh0 (h0 @ Whh0^T), 2 -> gh1 (h1 @ Whh1^T).
// Phase B (all 192 blocks): h0(t) update + gi1 (h0' @ Wih1^T).
// h1(t-1) is materialized by group 2 during phase A of step t (and consumed next step / epilogue).
__global__ __launch_bounds__(256) void gru_scan(
    const int* __restrict__ idx, const float* __restrict__ wte,
    const float* __restrict__ Wih, const float* __restrict__ bih,
    const float* __restrict__ Whh, const float* __restrict__ bhh,
    float* __restrict__ gi0, float* __restrict__ gh0, float* __restrict__ gh1,
    float* __restrict__ gi1, float* __restrict__ h0g, float* __restrict__ h1g,
    unsigned* __restrict__ barcnt)
{
  __shared__ float sVec[Bz][EP];
  __shared__ int sIdx[Bz];
  const int tid = threadIdx.x, bx = blockIdx.x;
  const int grp = bx/64, bsub = bx - grp*64;
  const int wv = tid>>6, lane = tid&63, bb = lane&15, gq = lane>>4;
  unsigned nsync = 0;

  for (int t=0; t<Tz; t++){
    // ---------- phase A staging ----------
    if (grp==0){
      if (tid<Bz) sIdx[tid] = idx[tid*Tz + t];
      __syncthreads();
      for (int i4=tid; i4<Bz*Ez/4; i4+=256){
        const int b = i4/(Ez/4), c = (i4 - b*(Ez/4))<<2;
        *(float4*)(&sVec[b][c]) = *(const float4*)(wte + (size_t)sIdx[b]*Ez + c);
      }
    } else if (grp==1){
      const float* h0p = h0g + ((t&1)^1)*(Bz*Ez);   // h0(t-1)
      for (int i4=tid; i4<Bz*Ez/4; i4+=256){
        const int b = i4/(Ez/4), c = (i4 - b*(Ez/4))<<2;
        float4 v;
        if (t==0){ v.x=v.y=v.z=v.w=0.f; } else { v = *(const float4*)(h0p + b*Ez + c); }
        *(float4*)(&sVec[b][c]) = v;
      }
    } else {
      if (t==0){
        for (int i=tid;i<Bz*Ez;i+=256){ const int b=i/Ez; sVec[b][i-b*Ez]=0.f; }
      } else {
        const float* h1old = h1g + (t&1)*(Bz*Ez);       // h1(t-2)
        float*       h1new = h1g + ((t&1)^1)*(Bz*Ez);   // h1(t-1)
        for (int i=tid;i<Bz*Ez;i+=256){
          const int b=i/Ez, c=i-b*Ez;
          const float hp = (t==1) ? 0.f : h1old[i];
          const float v = gru_h(gi1[b*E3+c], gi1[b*E3+Ez+c], gi1[b*E3+2*Ez+c],
                                gh1[b*E3+c], gh1[b*E3+Ez+c], gh1[b*E3+2*Ez+c], hp);
          sVec[b][c]=v;
          if (i/192==bsub) h1new[i]=v;   // each of 64 blocks writes a 192-elem slice
        }
      }
    }
    __syncthreads();

    // ---------- phase A matmul ----------
    {
      const float* Wm; const float* bs; float* op;
      if (grp==0){ Wm=Wih;                 bs=bih;     op=gi0; }
      else if (grp==1){ Wm=Whh;            bs=bhh;     op=gh0; }
      else { Wm=Whh+(size_t)E3*Ez;         bs=bhh+E3;  op=gh1; }
      const int r0 = bsub*36 + wv*9;
      mm_rows<4>(Wm,bs,sVec,op,r0,  bb,gq);
      mm_rows<4>(Wm,bs,sVec,op,r0+4,bb,gq);
      mm_rows<1>(Wm,bs,sVec,op,r0+8,bb,gq);
    }
    grid_barrier(barcnt, (++nsync)*NB);   // S1

    // ---------- phase B: h0 update + gi1 ----------
    {
      const float* h0old = h0g + ((t&1)^1)*(Bz*Ez);
      float*       h0new = h0g + (t&1)*(Bz*Ez);
      for (int i=tid;i<Bz*Ez;i+=256){
        const int b=i/Ez, c=i-b*Ez;
        const float hp = (t==0) ? 0.f : h0old[i];
        const float v = gru_h(gi0[b*E3+c], gi0[b*E3+Ez+c], gi0[b*E3+2*Ez+c],
                              gh0[b*E3+c], gh0[b*E3+Ez+c], gh0[b*E3+2*Ez+c], hp);
        sVec[b][c]=v;
        if ((i>>6)==bx) h0new[i]=v;      // each of 192 blocks writes a 64-elem slice
      }
      __syncthreads();
      mm_rows<3>(Wih+(size_t)E3*Ez, bih+E3, sVec, gi1, bx*12 + wv*3, bb, gq);
    }
    grid_barrier(barcnt, (++nsync)*NB);   // S2
  }
}

// h1(1023) = gru(gi1,gh1,h1g[0]); then LayerNorm*g -> ln
__global__ __launch_bounds__(256) void finalize_ln(
    const float* __restrict__ gi1, const float* __restrict__ gh1,
    const float* __restrict__ h1prev, const float* __restrict__ g,
    float* __restrict__ ln)
{
  __shared__ float sLast[Bz*Ez];
  const int tid=threadIdx.x;
  for (int i=tid;i<Bz*Ez;i+=256){
    const int b=i/Ez, c=i-b*Ez;
    sLast[i] = gru_h(gi1[b*E3+c], gi1[b*E3+Ez+c], gi1[b*E3+2*Ez+c],
                     gh1[b*E3+c], gh1[b*E3+Ez+c], gh1[b*E3+2*Ez+c], h1prev[i]);
  }
  __syncthreads();
  const int wv=tid>>6, lane=tid&63;
  for (int b=wv; b<Bz; b+=4){
    float s=0.f;
    for (int c=lane;c<Ez;c+=64) s += sLast[b*Ez+c];
#pragma unroll
    for (int off=32; off; off>>=1) s += __shfl_xor(s, off);
    const float mu = s/(float)Ez;
    float s2=0.f;
    for (int c=lane;c<Ez;c+=64){ const float d=sLast[b*Ez+c]-mu; s2=fmaf(d,d,s2); }
#pragma unroll
    for (int off=32; off; off>>=1) s2 += __shfl_xor(s2, off);
    const float inv = rsqrtf(s2/(float)Ez + LN_EPS);
    for (int c=lane;c<Ez;c+=64) ln[b*Ez+c] = (sLast[b*Ez+c]-mu)*inv*g[c];
  }
}

// logits[b,v] = dot(ln[b,:], wte[v,:]) ; 64 rows per block, 16 rows per wave.
__global__ __launch_bounds__(256) void lm_head(
    const float* __restrict__ ln, const float* __restrict__ wte,
    float* __restrict__ out)
{
  __shared__ float sLn[Bz][EP];
  const int tid=threadIdx.x;
  for (int i4=tid; i4<Bz*Ez/4; i4+=256){
    const int b=i4/(Ez/4), c=(i4-b*(Ez/4))<<2;
    *(float4*)(&sLn[b][c]) = *(const float4*)(ln + b*Ez + c);
  }
  __syncthreads();
  const int wv=tid>>6, lane=tid&63, rr=lane>>4, cl=lane&15;
  const int vbase = blockIdx.x*64 + wv*16 + rr;   // rows vbase + 4k, k=0..3
  float acc[4][16];
#pragma unroll
  for (int k=0;k<4;k++)
#pragma unroll
    for (int b=0;b<16;b++) acc[k][b]=0.f;

  for (int j=0;j<12;j++){
    const int c = (cl<<2) + (j<<6);
    float4 w4[4];
#pragma unroll
    for (int k=0;k<4;k++){
      const int v = vbase + 4*k;
      if (v < Vz) w4[k] = *(const float4*)(wte + (size_t)v*Ez + c);
      else { w4[k].x=w4[k].y=w4[k].z=w4[k].w=0.f; }
    }
#pragma unroll
    for (int b=0;b<16;b++){
      const float4 hv = *(const float4*)(&sLn[b][c]);
#pragma unroll
      for (int k=0;k<4;k++) acc[k][b] = dot4acc(acc[k][b], w4[k], hv);
    }
  }
#pragma unroll
  for (int off=1; off<16; off<<=1)
#pragma unroll
    for (int k=0;k<4;k++)
#pragma unroll
      for (int b=0;b<16;b++) acc[k][b] += __shfl_xor(acc[k][b], off);

  if (cl==0){
#pragma unroll
    for (int k=0;k<4;k++){
      const int v = vbase + 4*k;
      if (v < Vz){
#pragma unroll
        for (int b=0;b<16;b++) out[(size_t)b*Vz + v] = acc[k][b];
      }
    }
  }
}

extern "C" void kernel_launch(void* const* d_in, const int* in_sizes, int n_in,
                              void* d_out, int out_size, void* d_ws, size_t ws_size,
                              hipStream_t stream) {
  const int*   idx = (const int*)  d_in[0];
  const float* wte = (const float*)d_in[1];
  const float* Wih = (const float*)d_in[2];
  const float* bih = (const float*)d_in[3];
  const float* Whh = (const float*)d_in[4];
  const float* bhh = (const float*)d_in[5];
  const float* g   = (const float*)d_in[6];
  float* out = (float*)d_out;

  float* base = (float*)d_ws;
  unsigned* barcnt = (unsigned*)d_ws;        // words [0,64): barrier state
  float* gi0 = base + 64;
  float* gh0 = gi0 + Bz*E3;
  float* gh1 = gh0 + Bz*E3;
  float* gi1 = gh1 + Bz*E3;
  float* h0g = gi1 + Bz*E3;                  // 2 * B*E
  float* h1g = h0g + 2*Bz*Ez;                // 2 * B*E
  float* ln  = h1g + 2*Bz*Ez;                // B*E

  hipMemsetAsync(d_ws, 0, 256, stream);      // reset barrier each (re)play

  void* args[] = {(void*)&idx,(void*)&wte,(void*)&Wih,(void*)&bih,(void*)&Whh,(void*)&bhh,
                  (void*)&gi0,(void*)&gh0,(void*)&gh1,(void*)&gi1,(void*)&h0g,(void*)&h1g,
                  (void*)&barcnt};
  hipLaunchCooperativeKernel((void*)gru_scan, dim3(NB), dim3(256), args, 0, stream);

  finalize_ln<<<1, 256, 0, stream>>>(gi1, gh1, h1g, g, ln);
  lm_head<<<786, 256, 0, stream>>>(ln, wte, out);
}

// Round 2
// 36730.618 us; speedup vs baseline: 5.3192x; 5.3192x over previous
//
#include <hip/hip_runtime.h>
#include <math.h>

#define Bz 16
#define Tz 1024
#define Ez 768
#define E3 2304
#define Vz 50257
#define NBK 256          // 256 blocks: 128 layer-0, 128 layer-1, 6 columns each
#define LN_EPS 1e-5f
#define VEC (Bz*Ez)      // 12288 floats per h vector
#define EP 772           // padded LDS row stride

__device__ __forceinline__ float dot4acc(float acc, float4 w, float4 h){
  acc = fmaf(w.x,h.x,acc); acc = fmaf(w.y,h.y,acc);
  acc = fmaf(w.z,h.z,acc); acc = fmaf(w.w,h.w,acc);
  return acc;
}
__device__ __forceinline__ float sigm(float x){ return 1.0f/(1.0f+expf(-x)); }

// ---------------------------------------------------------------------------
// Persistent cooperative scan. Block bx: layer L = bx>>7, owns columns
// [c0, c0+6). Per super-step s: layer-0 computes h0(s) (s<T), layer-1
// computes h1(s-1) (s>=1). One grid barrier per super-step.
// Cross-block h exchange: relaxed agent-scope atomics (L2-bypass, coherent
// at L3) -> NO acquire/release fences -> weights stay resident in L2.
// ---------------------------------------------------------------------------
__global__ __launch_bounds__(256) void gru_scan(
    const int* __restrict__ idx, const float* __restrict__ wte,
    const float* __restrict__ Wih, const float* __restrict__ bih,
    const float* __restrict__ Whh, const float* __restrict__ bhh,
    float* __restrict__ h0g, float* __restrict__ h1g,
    unsigned* __restrict__ cnt)
{
  __shared__ float bufX0[Bz][EP];   // L0: x(t) ping   | L1: h0(t)
  __shared__ float bufX1[Bz][EP];   // L0: x(t) pong   | L1: unused
  __shared__ float bufH [Bz][EP];   // h_prev (own layer)
  __shared__ float gates[36][17];   // [row m][batch]
  __shared__ float biasS[36];

  const int tid = threadIdx.x, bx = blockIdx.x;
  const int L = bx>>7, sub = bx&127, c0 = sub*6;
  const int wv = tid>>6, lane = tid&63, kq = lane&15, bb = lane>>4;

  const float* WihL = Wih + (size_t)L*E3*Ez;
  const float* WhhL = Whh + (size_t)L*E3*Ez;

  // 9 weight-row pointers per wave. m = wv*9+r in [0,36):
  //  m<18 -> Wih rows (input = bufX), m>=18 -> Whh rows (input = bufH)
  //  within: g = (m%18)/6 gate (r,z,n), cc = m%6 column offset.
  const float* wrow[9];
#pragma unroll
  for (int r=0;r<9;r++){
    const int m = wv*9+r, mat = m/18, mm = m%18, g = mm/6, cc = mm-g*6;
    wrow[r] = (mat ? WhhL : WihL) + (size_t)(g*Ez + c0 + cc)*Ez;
  }
  if (tid<36){
    const int mat = tid/18, mm = tid%18, g = mm/6, cc = mm-g*6;
    biasS[tid] = (mat ? bhh : bih)[L*E3 + g*Ez + c0 + cc];
  }

  // preload x(0) for layer 0
  if (L==0){
#pragma unroll
    for (int k4=0;k4<12;k4++){
      const int i4 = tid + (k4<<8);
      const int b = i4/192, c4 = i4 - b*192;
      const int row = idx[b*Tz];
      *(float4*)&bufX0[b][c4<<2] = *(const float4*)(wte + (size_t)row*Ez + (c4<<2));
    }
  }
  __syncthreads();

  for (int s=0; s<=Tz; ++s){
    // ---- grid wait: all blocks finished super-step s-1 ----
    if (s>0){
      if (tid==0){
        const unsigned target = (unsigned)s*NBK;
        while (__hip_atomic_load(cnt, __ATOMIC_RELAXED, __HIP_MEMORY_SCOPE_AGENT) < target)
          __builtin_amdgcn_s_sleep(1);
      }
      __syncthreads();
    }

    const bool active = (L==0) ? (s<Tz) : (s>0);
    if (active){
      const int t = (L==0) ? s : s-1;

      // ---- stage phase: bypass-read h vectors into LDS ----
      if (L==0){
        if (t==0){
#pragma unroll
          for (int k=0;k<48;k++) bufH[k/3][tid + ((k%3)<<8)] = 0.f;
        } else {
          const float* hp = h0g + (size_t)((s-1)&1)*VEC;
#pragma unroll
          for (int k=0;k<48;k++){
            const float v = __hip_atomic_load(hp + tid + (k<<8),
                              __ATOMIC_RELAXED, __HIP_MEMORY_SCOPE_AGENT);
            bufH[k/3][tid + ((k%3)<<8)] = v;
          }
        }
      } else {
        const float* xp = h0g + (size_t)((s-1)&1)*VEC;   // h0(t)
#pragma unroll
        for (int k=0;k<48;k++){
          const float v = __hip_atomic_load(xp + tid + (k<<8),
                            __ATOMIC_RELAXED, __HIP_MEMORY_SCOPE_AGENT);
          bufX0[k/3][tid + ((k%3)<<8)] = v;
        }
        if (t==0){
#pragma unroll
          for (int k=0;k<48;k++) bufH[k/3][tid + ((k%3)<<8)] = 0.f;
        } else {
          const float* hp = h1g + (size_t)(s&1)*VEC;     // h1(t-1)
#pragma unroll
          for (int k=0;k<48;k++){
            const float v = __hip_atomic_load(hp + tid + (k<<8),
                              __ATOMIC_RELAXED, __HIP_MEMORY_SCOPE_AGENT);
            bufH[k/3][tid + ((k%3)<<8)] = v;
          }
        }
      }
      __syncthreads();

      // ---- matmul: 9 rows/wave x 16 batches, k split 16-way (kq) ----
      const float (*V)[EP];
      if (wv<2) V = (L==0) ? ((s&1) ? bufX1 : bufX0) : bufX0;
      else      V = bufH;

      float acc[9][4];
#pragma unroll
      for (int r=0;r<9;r++)
#pragma unroll
        for (int bi=0;bi<4;bi++) acc[r][bi]=0.f;

#pragma unroll 4
      for (int j=0;j<12;j++){
        const int kk = (j<<6) + (kq<<2);
        float4 wv4[9];
#pragma unroll
        for (int r=0;r<9;r++) wv4[r] = *(const float4*)(wrow[r] + kk);
#pragma unroll
        for (int bi=0;bi<4;bi++){
          const float4 hv = *(const float4*)&V[bb*4+bi][kk];
#pragma unroll
          for (int r=0;r<9;r++) acc[r][bi] = dot4acc(acc[r][bi], wv4[r], hv);
        }
      }
      // reduce over kq (low 4 lane bits)
#pragma unroll
      for (int r=0;r<9;r++)
#pragma unroll
        for (int bi=0;bi<4;bi++){
          float a = acc[r][bi];
          a += __shfl_xor(a,1); a += __shfl_xor(a,2);
          a += __shfl_xor(a,4); a += __shfl_xor(a,8);
          acc[r][bi]=a;
        }
      if (kq==0){
#pragma unroll
        for (int r=0;r<9;r++)
#pragma unroll
          for (int bi=0;bi<4;bi++) gates[wv*9+r][bb*4+bi] = acc[r][bi];
      }
      __syncthreads();

      // ---- nonlinearity + publish h-slice (96 threads: 16 b x 6 cols) ----
      if (tid < 96){
        const int b = tid&15, cc = tid>>4;
        const float gir = gates[cc   ][b] + biasS[cc];
        const float giz = gates[6+cc ][b] + biasS[6+cc];
        const float gin = gates[12+cc][b] + biasS[12+cc];
        const float ghr = gates[18+cc][b] + biasS[18+cc];
        const float ghz = gates[24+cc][b] + biasS[24+cc];
        const float ghn = gates[30+cc][b] + biasS[30+cc];
        const float r = sigm(gir+ghr);
        const float z = sigm(giz+ghz);
        const float n = tanhf(fmaf(r, ghn, gin));
        const float hp = bufH[b][c0+cc];
        const float hv = fmaf(z, hp - n, n);
        float* hOut = (L==0) ? (h0g + (size_t)(s&1)*VEC)
                             : (h1g + (size_t)((s-1)&1)*VEC);
        __hip_atomic_store(hOut + b*Ez + c0 + cc, hv,
                           __ATOMIC_RELAXED, __HIP_MEMORY_SCOPE_AGENT);
      }

      // ---- prefetch x(s+1) into the other X buffer (off critical path) ----
      if (L==0 && s+1 < Tz){
        float (*bx_)[EP] = ((s+1)&1) ? bufX1 : bufX0;
#pragma unroll
        for (int k4=0;k4<12;k4++){
          const int i4 = tid + (k4<<8);
          const int b = i4/192, c4 = i4 - b*192;
          const int row = idx[b*Tz + (s+1)];
          *(float4*)&bx_[b][c4<<2] = *(const float4*)(wte + (size_t)row*Ez + (c4<<2));
        }
      }
    }

    // ---- arrive (stores drained by the waitcnt inside __syncthreads) ----
    __syncthreads();
    if (tid==0)
      __hip_atomic_fetch_add(cnt, 1u, __ATOMIC_RELAXED, __HIP_MEMORY_SCOPE_AGENT);
  }
}

// LayerNorm of final h1 -> ln
__global__ __launch_bounds__(256) void finalize_ln(
    const float* __restrict__ h1, const float* __restrict__ g,
    float* __restrict__ ln)
{
  const int tid=threadIdx.x, wv=tid>>6, lane=tid&63;
  for (int b=wv; b<Bz; b+=4){
    float sum=0.f;
    for (int c=lane;c<Ez;c+=64) sum += h1[b*Ez+c];
#pragma unroll
    for (int off=32; off; off>>=1) sum += __shfl_xor(sum, off);
    const float mu = sum/(float)Ez;
    float s2=0.f;
    for (int c=lane;c<Ez;c+=64){ const float d=h1[b*Ez+c]-mu; s2=fmaf(d,d,s2); }
#pragma unroll
    for (int off=32; off; off>>=1) s2 += __shfl_xor(s2, off);
    const float inv = rsqrtf(s2/(float)Ez + LN_EPS);
    for (int c=lane;c<Ez;c+=64) ln[b*Ez+c] = (h1[b*Ez+c]-mu)*inv*g[c];
  }
}

// logits[b,v] = dot(ln[b,:], wte[v,:]) ; 64 rows per block, 16 rows per wave.
__global__ __launch_bounds__(256) void lm_head(
    const float* __restrict__ ln, const float* __restrict__ wte,
    float* __restrict__ out)
{
  __shared__ float sLn[Bz][EP];
  const int tid=threadIdx.x;
  for (int i4=tid; i4<Bz*Ez/4; i4+=256){
    const int b = i4/(Ez/4), c = (i4 - b*(Ez/4))<<2;
    *(float4*)(&sLn[b][c]) = *(const float4*)(ln + b*Ez + c);
  }
  __syncthreads();
  const int wv=tid>>6, lane=tid&63, rr=lane>>4, cl=lane&15;
  const int vbase = blockIdx.x*64 + wv*16 + rr;
  float acc[4][16];
#pragma unroll
  for (int k=0;k<4;k++)
#pragma unroll
    for (int b=0;b<16;b++) acc[k][b]=0.f;

  for (int j=0;j<12;j++){
    const int c = (cl<<2) + (j<<6);
    float4 w4[4];
#pragma unroll
    for (int k=0;k<4;k++){
      const int v = vbase + 4*k;
      if (v < Vz) w4[k] = *(const float4*)(wte + (size_t)v*Ez + c);
      else { w4[k].x=w4[k].y=w4[k].z=w4[k].w=0.f; }
    }
#pragma unroll
    for (int b=0;b<16;b++){
      const float4 hv = *(const float4*)(&sLn[b][c]);
#pragma unroll
      for (int k=0;k<4;k++) acc[k][b] = dot4acc(acc[k][b], w4[k], hv);
    }
  }
#pragma unroll
  for (int off=1; off<16; off<<=1)
#pragma unroll
    for (int k=0;k<4;k++)
#pragma unroll
      for (int b=0;b<16;b++) acc[k][b] += __shfl_xor(acc[k][b], off);

  if (cl==0){
#pragma unroll
    for (int k=0;k<4;k++){
      const int v = vbase + 4*k;
      if (v < Vz){
#pragma unroll
        for (int b=0;b<16;b++) out[(size_t)b*Vz + v] = acc[k][b];
      }
    }
  }
}

extern "C" void kernel_launch(void* const* d_in, const int* in_sizes, int n_in,
                              void* d_out, int out_size, void* d_ws, size_t ws_size,
                              hipStream_t stream) {
  const int*   idx = (const int*)  d_in[0];
  const float* wte = (const float*)d_in[1];
  const float* Wih = (const float*)d_in[2];
  const float* bih = (const float*)d_in[3];
  const float* Whh = (const float*)d_in[4];
  const float* bhh = (const float*)d_in[5];
  const float* g   = (const float*)d_in[6];
  float* out = (float*)d_out;

  float* base = (float*)d_ws;
  unsigned* cnt = (unsigned*)d_ws;           // words [0,64): barrier counter
  float* h0g = base + 64;                    // 2 * B*E
  float* h1g = h0g + 2*VEC;                  // 2 * B*E
  float* ln  = h1g + 2*VEC;                  // B*E

  hipMemsetAsync(d_ws, 0, 256, stream);      // reset barrier each (re)play

  void* args[] = {(void*)&idx,(void*)&wte,(void*)&Wih,(void*)&bih,
                  (void*)&Whh,(void*)&bhh,(void*)&h0g,(void*)&h1g,(void*)&cnt};
  hipLaunchCooperativeKernel((void*)gru_scan, dim3(NBK), dim3(256), args, 0, stream);

  // final h1(1023) lives in h1g[(Tz-1)&1] = h1g + VEC
  finalize_ln<<<1, 256, 0, stream>>>(h1g + VEC, g, ln);
  lm_head<<<786, 256, 0, stream>>>(ln, wte, out);
}